// Round 1
// baseline (534.588 us; speedup 1.0000x reference)
//
#include <hip/hip_runtime.h>
#include <hip/hip_bf16.h>
#include <stdint.h>

#define BB 4
#define TT 2048
#define CC 1024
#define HH 8
#define DD 128

typedef unsigned short u16;
typedef unsigned int u32;
typedef __attribute__((ext_vector_type(4))) float f32x4;
typedef __attribute__((ext_vector_type(8))) __bf16 bf16x8;

__device__ __forceinline__ float bf2f(u16 u){ u32 x=((u32)u)<<16; float f; __builtin_memcpy(&f,&x,4); return f; }
__device__ __forceinline__ u16 f2bf(float f){ u32 x; __builtin_memcpy(&x,&f,4); x += 0x7fffu + ((x>>16)&1u); return (u16)(x>>16); }

__device__ __forceinline__ void gload16(const void* g, void* l){
  __builtin_amdgcn_global_load_lds((const __attribute__((address_space(1))) u32*)g,
                                   (__attribute__((address_space(3))) u32*)l, 16, 0, 0);
}
__device__ __forceinline__ f32x4 mfma16(bf16x8 a, bf16x8 b, f32x4 c){
  return __builtin_amdgcn_mfma_f32_16x16x32_bf16(a,b,c,0,0,0);
}

// ---------------- LayerNorm: f32 x -> bf16 xn ----------------
__global__ void ln_k(const float* __restrict__ x, const float* __restrict__ g,
                     const float* __restrict__ bta, u16* __restrict__ xn){
  int row = blockIdx.x, tid = threadIdx.x;
  const float4 v = ((const float4*)(x + (size_t)row*CC))[tid];
  float s = v.x+v.y+v.z+v.w;
  float ss = v.x*v.x+v.y*v.y+v.z*v.z+v.w*v.w;
  #pragma unroll
  for(int m=1;m<64;m<<=1){ s += __shfl_xor(s,m); ss += __shfl_xor(ss,m); }
  __shared__ float red[8];
  if((tid&63)==0){ red[tid>>6]=s; red[4+(tid>>6)]=ss; }
  __syncthreads();
  float ts = red[0]+red[1]+red[2]+red[3];
  float tss = red[4]+red[5]+red[6]+red[7];
  float mu = ts*(1.0f/CC);
  float rs = rsqrtf(tss*(1.0f/CC) - mu*mu + 1e-5f);
  int c0 = tid*4;
  ushort4 o;
  o.x = f2bf((v.x-mu)*rs*g[c0+0]+bta[c0+0]);
  o.y = f2bf((v.y-mu)*rs*g[c0+1]+bta[c0+1]);
  o.z = f2bf((v.z-mu)*rs*g[c0+2]+bta[c0+2]);
  o.w = f2bf((v.w-mu)*rs*g[c0+3]+bta[c0+3]);
  ((ushort4*)(xn + (size_t)row*CC))[tid] = o;
}

// ---------------- weights f32 -> bf16 (Wq|Wk|Wv|Wo contiguous) ----------------
__global__ void wconv_k(const float* __restrict__ wq, const float* __restrict__ wk,
                        const float* __restrict__ wv, const float* __restrict__ wo,
                        u16* __restrict__ out){
  int i = blockIdx.x*256 + threadIdx.x;   // [0, 1048576) float4s
  int sel = i>>18;
  const float* src = sel==0?wq: sel==1?wk: sel==2?wv:wo;
  float4 v = ((const float4*)src)[i & 262143];
  ushort4 o; o.x=f2bf(v.x); o.y=f2bf(v.y); o.z=f2bf(v.z); o.w=f2bf(v.w);
  ((ushort4*)out)[i] = o;
}

// ---------------- RoPE tables [T][64] ----------------
__global__ void rope_tab_k(float* __restrict__ cosT, float* __restrict__ sinT){
  int i = blockIdx.x*256 + threadIdx.x;  // 131072
  int t = i>>6, j = i&63;
  float inv = powf(10000.0f, -(float)(2*j)*(1.0f/128.0f));
  float a = (float)t * inv;
  cosT[i] = cosf(a);
  sinT[i] = sinf(a);
}

// ---------------- RoPE apply in-place on Q,K (bf16) ----------------
__global__ void rope_apply_k(u16* __restrict__ Qb, u16* __restrict__ Kb,
                             const float* __restrict__ cosT, const float* __restrict__ sinT){
  int bt = blockIdx.x, tid = threadIdx.x;
  int t = bt & (TT-1);
  #pragma unroll
  for(int pp=0; pp<2; pp++){
    int p = tid*2+pp;
    int h = p>>6, d = p&63;
    size_t i1 = (size_t)bt*CC + h*DD + d;
    float c = cosT[t*64+d], s = sinT[t*64+d];
    float q1 = bf2f(Qb[i1]), q2 = bf2f(Qb[i1+64]);
    Qb[i1]    = f2bf(q1*c - q2*s);
    Qb[i1+64] = f2bf(q2*c + q1*s);
    float k1 = bf2f(Kb[i1]), k2 = bf2f(Kb[i1+64]);
    Kb[i1]    = f2bf(k1*c - k2*s);
    Kb[i1+64] = f2bf(k2*c + k1*s);
  }
}

// ---------------- qp/kp = first-3-dims dot head_dirs ----------------
__global__ void qpkp_k(const u16* __restrict__ Qb, const u16* __restrict__ Kb,
                       const float* __restrict__ dirs, float* __restrict__ qp, float* __restrict__ kp){
  int idx = blockIdx.x*256 + threadIdx.x;  // [0, 65536) = (b*H+h)*T + t
  int b = idx>>14, rem = idx & 16383;
  int h = rem>>11, t = rem & 2047;
  size_t base = ((size_t)(b*TT + t))*CC + h*DD;
  float d0 = dirs[h*3], d1 = dirs[h*3+1], d2 = dirs[h*3+2];
  qp[idx] = bf2f(Qb[base])*d0 + bf2f(Qb[base+1])*d1 + bf2f(Qb[base+2])*d2;
  kp[idx] = bf2f(Kb[base])*d0 + bf2f(Kb[base+1])*d1 + bf2f(Kb[base+2])*d2;
}

// ---------------- GEMM: out[M,N] = A[M,K] * W[N,K]^T ----------------
// MODE 0: bf16 row-major out. MODE 1: bf16 out transposed to (B,H,D,T). MODE 2: f32 out + resid.
template<int MODE>
__global__ __launch_bounds__(256) void gemm_k(const u16* __restrict__ A, const u16* __restrict__ W,
                                              u16* __restrict__ outb, float* __restrict__ outf,
                                              const float* __restrict__ resid){
  __shared__ __align__(16) u16 As[128*64];
  __shared__ __align__(16) u16 Bs[128*64];
  const int K = CC;
  int m0 = blockIdx.x*128, n0 = blockIdx.y*128;
  int tid = threadIdx.x, w = tid>>6, l = tid&63;
  int li = l&15, lg = l>>4;
  int wm = w>>1, wn = w&1;
  f32x4 acc[4][4] = {};
  for(int k0=0; k0<K; k0+=64){
    #pragma unroll
    for(int i=0;i<4;i++){
      int L = (w*4+i)*1024 + l*16;
      int row = L>>7;
      int colb = (L&127) ^ ((row&7)<<4);   // inverse-swizzled source (rule #21)
      gload16(A + ((size_t)(m0+row)*K + k0 + (colb>>1)), (char*)As + (w*4+i)*1024);
      gload16(W + ((size_t)(n0+row)*K + k0 + (colb>>1)), (char*)Bs + (w*4+i)*1024);
    }
    __syncthreads();
    #pragma unroll
    for(int kc=0;kc<2;kc++){
      bf16x8 af[4], bfr[4];
      #pragma unroll
      for(int mi=0;mi<4;mi++){
        int row = wm*64 + mi*16 + li;
        int colb = (kc*64 + lg*16) ^ ((row&7)<<4);
        af[mi] = *(const bf16x8*)((const char*)As + row*128 + colb);
      }
      #pragma unroll
      for(int ni=0;ni<4;ni++){
        int row = wn*64 + ni*16 + li;
        int colb = (kc*64 + lg*16) ^ ((row&7)<<4);
        bfr[ni] = *(const bf16x8*)((const char*)Bs + row*128 + colb);
      }
      #pragma unroll
      for(int mi=0;mi<4;mi++){
        #pragma unroll
        for(int ni=0;ni<4;ni++)
          acc[mi][ni] = mfma16(af[mi], bfr[ni], acc[mi][ni]);
      }
    }
    __syncthreads();
  }
  #pragma unroll
  for(int mi=0;mi<4;mi++){
    #pragma unroll
    for(int ni=0;ni<4;ni++){
      #pragma unroll
      for(int r=0;r<4;r++){
        int row = m0 + wm*64 + mi*16 + lg*4 + r;   // C/D: row=(l>>4)*4+reg
        int col = n0 + wn*64 + ni*16 + li;         //      col=l&15
        float v = acc[mi][ni][r];
        if(MODE==0){
          outb[(size_t)row*CC + col] = f2bf(v);
        } else if(MODE==1){
          int hh = col>>7, dd = col&127, bb = row>>11, t = row&2047;
          outb[(((size_t)bb*HH+hh)*DD+dd)*TT + t] = f2bf(v);
        } else {
          size_t o = (size_t)row*CC + col;
          outf[o] = v + resid[o];
        }
      }
    }
  }
}

// ---------------- fused dual flash attention ----------------
__global__ __launch_bounds__(256) void attn_k(const u16* __restrict__ Q, const u16* __restrict__ Kb,
                                              const u16* __restrict__ VT, const float* __restrict__ qp,
                                              const float* __restrict__ kp, const float* __restrict__ hs,
                                              u16* __restrict__ outp){
  __shared__ __align__(16) u16 Ks[64*128];     // [krow][d], 256B rows, XOR-swizzled
  __shared__ __align__(16) u16 Vs[128*64];     // V^T: [d][krow], 128B rows, XOR-swizzled
  __shared__ __align__(16) u16 Ps[4][16*64];   // per-wave P, 128B rows, XOR-swizzled
  __shared__ __align__(16) u16 P2s[4][16*64];
  int qt = blockIdx.x, bh = blockIdx.y;
  int b = bh>>3, h = bh&7;
  int tid = threadIdx.x, w = tid>>6, l = tid&63;
  int li = l&15, lg = l>>4;
  int q0 = qt*64 + w*16;

  bf16x8 qf[4];
  {
    const u16* qbase = Q + ((size_t)(b*TT + q0 + li)*CC + h*DD);
    #pragma unroll
    for(int c=0;c<4;c++) qf[c] = *(const bf16x8*)(qbase + c*32 + lg*8);
  }
  float qpv[4];
  #pragma unroll
  for(int r=0;r<4;r++) qpv[r] = qp[(size_t)bh*TT + q0 + lg*4 + r];

  float m1[4], l1[4], m2[4], l2[4];
  #pragma unroll
  for(int r=0;r<4;r++){ m1[r]=-__builtin_inff(); l1[r]=0.f; m2[r]=-__builtin_inff(); l2[r]=0.f; }
  f32x4 a1[8] = {}, a2[8] = {};
  const float scale = 0.08838834764831845f;  // 1/sqrt(128)

  for(int kt=0; kt<=qt; ++kt){
    int kbase = kt*64;
    #pragma unroll
    for(int i=0;i<4;i++){   // stage K tile
      int L = (w*4+i)*1024 + l*16;
      int row = L>>8;
      int colb = (L&255) ^ ((row&7)<<4);
      gload16(Kb + ((size_t)(b*TT + kbase + row)*CC + h*DD + (colb>>1)), (char*)Ks + (w*4+i)*1024);
    }
    #pragma unroll
    for(int i=0;i<4;i++){   // stage V^T tile
      int L = (w*4+i)*1024 + l*16;
      int row = L>>7;
      int colb = (L&127) ^ ((row&7)<<4);
      gload16(VT + (((size_t)bh*DD + row)*TT + kbase + (colb>>1)), (char*)Vs + (w*4+i)*1024);
    }
    __syncthreads();

    f32x4 sa[4] = {};
    #pragma unroll
    for(int c=0;c<4;c++){
      bf16x8 kf[4];
      #pragma unroll
      for(int nt=0;nt<4;nt++){
        int row = nt*16 + li;
        int colb = (c*64 + lg*16) ^ ((row&7)<<4);
        kf[nt] = *(const bf16x8*)((const char*)Ks + row*256 + colb);
      }
      #pragma unroll
      for(int nt=0;nt<4;nt++) sa[nt] = mfma16(qf[c], kf[nt], sa[nt]);
    }

    float kpv[4];
    #pragma unroll
    for(int nt=0;nt<4;nt++) kpv[nt] = kp[(size_t)bh*TT + kbase + nt*16 + li];

    bool diag = (kt==qt);
    float p1[4][4], p2[4][4];
    #pragma unroll
    for(int nt=0;nt<4;nt++){
      #pragma unroll
      for(int r=0;r<4;r++){
        float sv = sa[nt][r]*scale;
        float gv = qpv[r]*kpv[nt];
        if(diag){
          int kg = kbase + nt*16 + li;
          int qg = q0 + lg*4 + r;
          if(kg>qg){ sv = -__builtin_inff(); gv = -__builtin_inff(); }
        }
        p1[nt][r] = sv; p2[nt][r] = gv;
      }
    }

    #pragma unroll
    for(int r=0;r<4;r++){
      float mx = fmaxf(fmaxf(p1[0][r],p1[1][r]),fmaxf(p1[2][r],p1[3][r]));
      float gx = fmaxf(fmaxf(p2[0][r],p2[1][r]),fmaxf(p2[2][r],p2[3][r]));
      #pragma unroll
      for(int sm=1; sm<16; sm<<=1){ mx = fmaxf(mx, __shfl_xor(mx,sm)); gx = fmaxf(gx, __shfl_xor(gx,sm)); }
      float mn1 = fmaxf(m1[r], mx), mn2 = fmaxf(m2[r], gx);
      float c1 = __expf(m1[r]-mn1), c2 = __expf(m2[r]-mn2);
      float rs1=0.f, rs2=0.f;
      #pragma unroll
      for(int nt=0;nt<4;nt++){
        float e1 = __expf(p1[nt][r]-mn1); p1[nt][r]=e1; rs1+=e1;
        float e2 = __expf(p2[nt][r]-mn2); p2[nt][r]=e2; rs2+=e2;
      }
      #pragma unroll
      for(int sm=1; sm<16; sm<<=1){ rs1 += __shfl_xor(rs1,sm); rs2 += __shfl_xor(rs2,sm); }
      l1[r] = l1[r]*c1 + rs1; m1[r]=mn1;
      l2[r] = l2[r]*c2 + rs2; m2[r]=mn2;
      #pragma unroll
      for(int dt=0;dt<8;dt++){ a1[dt][r]*=c1; a2[dt][r]*=c2; }
    }

    #pragma unroll
    for(int nt=0;nt<4;nt++){
      #pragma unroll
      for(int r=0;r<4;r++){
        int qrow = lg*4+r;
        int off = (qrow*128 + (nt*16+li)*2) ^ ((qrow&7)<<4);
        *(u16*)((char*)Ps[w]  + off) = f2bf(p1[nt][r]);
        *(u16*)((char*)P2s[w] + off) = f2bf(p2[nt][r]);
      }
    }

    #pragma unroll
    for(int c=0;c<2;c++){
      int colb0 = c*64 + lg*16;
      int poff = (li*128 + colb0) ^ ((li&7)<<4);
      bf16x8 pf1 = *(const bf16x8*)((const char*)Ps[w]  + poff);
      bf16x8 pf2 = *(const bf16x8*)((const char*)P2s[w] + poff);
      #pragma unroll
      for(int dt=0;dt<8;dt++){
        int vrow = dt*16 + li;
        int vcolb = colb0 ^ ((vrow&7)<<4);
        bf16x8 vf = *(const bf16x8*)((const char*)Vs + vrow*128 + vcolb);
        a1[dt] = mfma16(pf1, vf, a1[dt]);
        a2[dt] = mfma16(pf2, vf, a2[dt]);
      }
    }
    __syncthreads();
  }

  float sh = hs[h];
  #pragma unroll
  for(int dt=0;dt<8;dt++){
    #pragma unroll
    for(int r=0;r<4;r++){
      float o1 = a1[dt][r]/l1[r];
      float o2 = a2[dt][r]/l2[r];
      float o = o1 + sh*(o2-o1);
      int qg = q0 + lg*4 + r;
      outp[(size_t)(b*TT+qg)*CC + h*DD + dt*16 + li] = f2bf(o);
    }
  }
}

extern "C" void kernel_launch(void* const* d_in, const int* in_sizes, int n_in,
                              void* d_out, int out_size, void* d_ws, size_t ws_size,
                              hipStream_t stream){
  (void)in_sizes; (void)n_in; (void)out_size; (void)ws_size;
  const float* x   = (const float*)d_in[0];
  const float* Wq  = (const float*)d_in[1];
  const float* Wk  = (const float*)d_in[2];
  const float* Wv  = (const float*)d_in[3];
  const float* Wo  = (const float*)d_in[4];
  const float* lng = (const float*)d_in[5];
  const float* lnb = (const float*)d_in[6];
  const float* hsc = (const float*)d_in[7];
  const float* hdr = (const float*)d_in[8];

  char* ws = (char*)d_ws;
  const size_t SZ = (size_t)8192*1024*2;       // 16 MiB per bf16 activation buffer
  u16* xn   = (u16*)ws;                        // reused as attn_out after QKV gemms
  u16* wbf  = (u16*)(ws + SZ);                 // 8 MiB: Wq|Wk|Wv|Wo bf16
  u16* Qb   = (u16*)(ws + SZ + 8388608);
  u16* Kb   = (u16*)(ws + 2*SZ + 8388608);
  u16* VT   = (u16*)(ws + 3*SZ + 8388608);     // (B,H,D,T)
  float* cosT = (float*)(ws + 4*SZ + 8388608);
  float* sinT = cosT + 131072;
  float* qp   = sinT + 131072;
  float* kp   = qp + 65536;

  ln_k<<<8192,256,0,stream>>>(x, lng, lnb, xn);
  wconv_k<<<4096,256,0,stream>>>(Wq,Wk,Wv,Wo,wbf);
  rope_tab_k<<<512,256,0,stream>>>(cosT,sinT);
  gemm_k<0><<<dim3(64,8),256,0,stream>>>(xn, wbf,          Qb, nullptr, nullptr);
  gemm_k<0><<<dim3(64,8),256,0,stream>>>(xn, wbf+1048576,  Kb, nullptr, nullptr);
  gemm_k<1><<<dim3(64,8),256,0,stream>>>(xn, wbf+2097152,  VT, nullptr, nullptr);
  rope_apply_k<<<8192,256,0,stream>>>(Qb,Kb,cosT,sinT);
  qpkp_k<<<256,256,0,stream>>>(Qb,Kb,hdr,qp,kp);
  attn_k<<<dim3(32,32),256,0,stream>>>(Qb,Kb,VT,qp,kp,hsc,xn);
  gemm_k<2><<<dim3(64,8),256,0,stream>>>(xn, wbf+3145728, nullptr, (float*)d_out, x);
}

// Round 2
// 471.375 us; speedup vs baseline: 1.1341x; 1.1341x over previous
//
#include <hip/hip_runtime.h>
#include <hip/hip_bf16.h>
#include <stdint.h>

#define BB 4
#define TT 2048
#define CC 1024
#define HH 8
#define DD 128

typedef unsigned short u16;
typedef unsigned int u32;
typedef unsigned long long u64;
typedef __attribute__((ext_vector_type(4))) float f32x4;
typedef __attribute__((ext_vector_type(8))) __bf16 bf16x8;

__device__ __forceinline__ float bf2f(u16 u){ u32 x=((u32)u)<<16; float f; __builtin_memcpy(&f,&x,4); return f; }
__device__ __forceinline__ u16 f2bf(float f){ u32 x; __builtin_memcpy(&x,&f,4); x += 0x7fffu + ((x>>16)&1u); return (u16)(x>>16); }

__device__ __forceinline__ void gload16(const void* g, void* l){
  __builtin_amdgcn_global_load_lds((const __attribute__((address_space(1))) u32*)g,
                                   (__attribute__((address_space(3))) u32*)l, 16, 0, 0);
}
__device__ __forceinline__ f32x4 mfma16(bf16x8 a, bf16x8 b, f32x4 c){
  return __builtin_amdgcn_mfma_f32_16x16x32_bf16(a,b,c,0,0,0);
}

// ---------------- LayerNorm: f32 x -> bf16 xn ----------------
__global__ void ln_k(const float* __restrict__ x, const float* __restrict__ g,
                     const float* __restrict__ bta, u16* __restrict__ xn){
  int row = blockIdx.x, tid = threadIdx.x;
  const float4 v = ((const float4*)(x + (size_t)row*CC))[tid];
  float s = v.x+v.y+v.z+v.w;
  float ss = v.x*v.x+v.y*v.y+v.z*v.z+v.w*v.w;
  #pragma unroll
  for(int m=1;m<64;m<<=1){ s += __shfl_xor(s,m); ss += __shfl_xor(ss,m); }
  __shared__ float red[8];
  if((tid&63)==0){ red[tid>>6]=s; red[4+(tid>>6)]=ss; }
  __syncthreads();
  float ts = red[0]+red[1]+red[2]+red[3];
  float tss = red[4]+red[5]+red[6]+red[7];
  float mu = ts*(1.0f/CC);
  float rs = rsqrtf(tss*(1.0f/CC) - mu*mu + 1e-5f);
  int c0 = tid*4;
  ushort4 o;
  o.x = f2bf((v.x-mu)*rs*g[c0+0]+bta[c0+0]);
  o.y = f2bf((v.y-mu)*rs*g[c0+1]+bta[c0+1]);
  o.z = f2bf((v.z-mu)*rs*g[c0+2]+bta[c0+2]);
  o.w = f2bf((v.w-mu)*rs*g[c0+3]+bta[c0+3]);
  ((ushort4*)(xn + (size_t)row*CC))[tid] = o;
}

// ---------------- weights f32 -> bf16 (Wq|Wk|Wv|Wo contiguous) ----------------
__global__ void wconv_k(const float* __restrict__ wq, const float* __restrict__ wk,
                        const float* __restrict__ wv, const float* __restrict__ wo,
                        u16* __restrict__ out){
  int i = blockIdx.x*256 + threadIdx.x;   // [0, 1048576) float4s
  int sel = i>>18;
  const float* src = sel==0?wq: sel==1?wk: sel==2?wv:wo;
  float4 v = ((const float4*)src)[i & 262143];
  ushort4 o; o.x=f2bf(v.x); o.y=f2bf(v.y); o.z=f2bf(v.z); o.w=f2bf(v.w);
  ((ushort4*)out)[i] = o;
}

// ---------------- RoPE tables [T][64] ----------------
__global__ void rope_tab_k(float* __restrict__ cosT, float* __restrict__ sinT){
  int i = blockIdx.x*256 + threadIdx.x;  // 131072
  int t = i>>6, j = i&63;
  float inv = powf(10000.0f, -(float)(2*j)*(1.0f/128.0f));
  float a = (float)t * inv;
  cosT[i] = cosf(a);
  sinT[i] = sinf(a);
}

// ---------------- RoPE apply in-place on Q,K (bf16) ----------------
__global__ void rope_apply_k(u16* __restrict__ Qb, u16* __restrict__ Kb,
                             const float* __restrict__ cosT, const float* __restrict__ sinT){
  int bt = blockIdx.x, tid = threadIdx.x;
  int t = bt & (TT-1);
  #pragma unroll
  for(int pp=0; pp<2; pp++){
    int p = tid*2+pp;
    int h = p>>6, d = p&63;
    size_t i1 = (size_t)bt*CC + h*DD + d;
    float c = cosT[t*64+d], s = sinT[t*64+d];
    float q1 = bf2f(Qb[i1]), q2 = bf2f(Qb[i1+64]);
    Qb[i1]    = f2bf(q1*c - q2*s);
    Qb[i1+64] = f2bf(q2*c + q1*s);
    float k1 = bf2f(Kb[i1]), k2 = bf2f(Kb[i1+64]);
    Kb[i1]    = f2bf(k1*c - k2*s);
    Kb[i1+64] = f2bf(k2*c + k1*s);
  }
}

// ---------------- qp/kp = first-3-dims dot head_dirs ----------------
__global__ void qpkp_k(const u16* __restrict__ Qb, const u16* __restrict__ Kb,
                       const float* __restrict__ dirs, float* __restrict__ qp, float* __restrict__ kp){
  int idx = blockIdx.x*256 + threadIdx.x;  // [0, 65536) = (b*H+h)*T + t
  int b = idx>>14, rem = idx & 16383;
  int h = rem>>11, t = rem & 2047;
  size_t base = ((size_t)(b*TT + t))*CC + h*DD;
  float d0 = dirs[h*3], d1 = dirs[h*3+1], d2 = dirs[h*3+2];
  qp[idx] = bf2f(Qb[base])*d0 + bf2f(Qb[base+1])*d1 + bf2f(Qb[base+2])*d2;
  kp[idx] = bf2f(Kb[base])*d0 + bf2f(Kb[base+1])*d1 + bf2f(Kb[base+2])*d2;
}

// ---------------- GEMM: out[M,N] = A[M,K] * W[N,K]^T ----------------
template<int MODE>
__global__ __launch_bounds__(256) void gemm_k(const u16* __restrict__ A, const u16* __restrict__ W,
                                              u16* __restrict__ outb, float* __restrict__ outf,
                                              const float* __restrict__ resid){
  __shared__ __align__(16) u16 As[128*64];
  __shared__ __align__(16) u16 Bs[128*64];
  const int K = CC;
  int m0 = blockIdx.x*128, n0 = blockIdx.y*128;
  int tid = threadIdx.x, w = tid>>6, l = tid&63;
  int li = l&15, lg = l>>4;
  int wm = w>>1, wn = w&1;
  f32x4 acc[4][4] = {};
  for(int k0=0; k0<K; k0+=64){
    #pragma unroll
    for(int i=0;i<4;i++){
      int L = (w*4+i)*1024 + l*16;
      int row = L>>7;
      int colb = (L&127) ^ ((row&7)<<4);
      gload16(A + ((size_t)(m0+row)*K + k0 + (colb>>1)), (char*)As + (w*4+i)*1024);
      gload16(W + ((size_t)(n0+row)*K + k0 + (colb>>1)), (char*)Bs + (w*4+i)*1024);
    }
    __syncthreads();
    #pragma unroll
    for(int kc=0;kc<2;kc++){
      bf16x8 af[4], bfr[4];
      #pragma unroll
      for(int mi=0;mi<4;mi++){
        int row = wm*64 + mi*16 + li;
        int colb = (kc*64 + lg*16) ^ ((row&7)<<4);
        af[mi] = *(const bf16x8*)((const char*)As + row*128 + colb);
      }
      #pragma unroll
      for(int ni=0;ni<4;ni++){
        int row = wn*64 + ni*16 + li;
        int colb = (kc*64 + lg*16) ^ ((row&7)<<4);
        bfr[ni] = *(const bf16x8*)((const char*)Bs + row*128 + colb);
      }
      #pragma unroll
      for(int mi=0;mi<4;mi++){
        #pragma unroll
        for(int ni=0;ni<4;ni++)
          acc[mi][ni] = mfma16(af[mi], bfr[ni], acc[mi][ni]);
      }
    }
    __syncthreads();
  }
  #pragma unroll
  for(int mi=0;mi<4;mi++){
    #pragma unroll
    for(int ni=0;ni<4;ni++){
      #pragma unroll
      for(int r=0;r<4;r++){
        int row = m0 + wm*64 + mi*16 + lg*4 + r;
        int col = n0 + wn*64 + ni*16 + li;
        float v = acc[mi][ni][r];
        if(MODE==0){
          outb[(size_t)row*CC + col] = f2bf(v);
        } else if(MODE==1){
          int hh = col>>7, dd = col&127, bb = row>>11, t = row&2047;
          outb[(((size_t)bb*HH+hh)*DD+dd)*TT + t] = f2bf(v);
        } else {
          size_t o = (size_t)row*CC + col;
          outf[o] = v + resid[o];
        }
      }
    }
  }
}

// ---------------- fused dual flash attention (swapped-operand, in-lane softmax) ----------------
__global__ __launch_bounds__(256) void attn_k(const u16* __restrict__ Q, const u16* __restrict__ Kb,
                                              const u16* __restrict__ VT, const float* __restrict__ qp,
                                              const float* __restrict__ kp, const float* __restrict__ hs,
                                              u16* __restrict__ outp){
  __shared__ __align__(16) u16 Ks[2][64*128];   // double-buffered K tiles
  __shared__ __align__(16) u16 Vs[2][128*64];   // double-buffered V^T tiles
  __shared__ __align__(16) u16 Ps[4][16*64];    // per-wave P (regular)
  __shared__ __align__(16) u16 P2s[4][16*64];   // per-wave P (geo)
  int qt = (int)gridDim.x - 1 - (int)blockIdx.x;   // long blocks dispatch first
  int bh = blockIdx.y;
  int b = bh>>3, h = bh&7;
  int tid = threadIdx.x, w = tid>>6, l = tid&63;
  int li = l&15, lg = l>>4;
  int q0 = qt*64 + w*16;
  int q  = q0 + li;                    // this lane's q-row (everything lane-local)

  bf16x8 qf[4];
  {
    const u16* qbase = Q + ((size_t)(b*TT + q)*CC + h*DD);
    #pragma unroll
    for(int c=0;c<4;c++) qf[c] = *(const bf16x8*)(qbase + c*32 + lg*8);
  }
  const float L2E = 1.442695040888963f;
  float qpl2 = qp[(size_t)bh*TT + q] * L2E;
  const float sl2 = 0.08838834764831845f * L2E;   // 1/sqrt(128) * log2(e)

  float m1=-__builtin_inff(), l1=0.f, m2=-__builtin_inff(), l2=0.f;
  f32x4 a1[8] = {}, a2[8] = {};

  auto stage = [&](int kt, int buf){
    int kbase = kt*64;
    #pragma unroll
    for(int i=0;i<4;i++){
      int L = (w*4+i)*1024 + l*16;
      {
        int row = L>>8;
        int colb = (L&255) ^ ((row&7)<<4);
        gload16(Kb + ((size_t)(b*TT + kbase + row)*CC + h*DD + (colb>>1)), (char*)Ks[buf] + (w*4+i)*1024);
      }
      {
        int row = L>>7;
        int colb = (L&127) ^ ((row&7)<<4);
        gload16(VT + (((size_t)bh*DD + row)*TT + kbase + (colb>>1)), (char*)Vs[buf] + (w*4+i)*1024);
      }
    }
  };

  stage(0, 0);
  __syncthreads();
  int cur = 0;

  for(int kt=0; kt<=qt; ++kt){
    if(kt < qt) stage(kt+1, cur^1);   // overlap next-tile loads with this tile's compute
    int kbase = kt*64;

    // ---- S^T = K · Q^T : lane holds S[k][q=li] for k = kbase + nt*16 + lg*4 + r ----
    f32x4 sa[4] = {};
    #pragma unroll
    for(int c=0;c<4;c++){
      bf16x8 kf[4];
      #pragma unroll
      for(int nt=0;nt<4;nt++){
        int row = nt*16 + li;
        int colb = (c*64 + lg*16) ^ ((row&7)<<4);
        kf[nt] = *(const bf16x8*)((const char*)Ks[cur] + row*256 + colb);
      }
      __builtin_amdgcn_s_setprio(1);
      #pragma unroll
      for(int nt=0;nt<4;nt++) sa[nt] = mfma16(kf[nt], qf[c], sa[nt]);
      __builtin_amdgcn_s_setprio(0);
    }

    // ---- scores in log2 domain ----
    const f32x4* kp4 = (const f32x4*)(kp + (size_t)bh*TT + kbase);
    bool diag = (kt==qt);
    float p1v[4][4], p2v[4][4];
    #pragma unroll
    for(int nt=0;nt<4;nt++){
      f32x4 kq = kp4[nt*4 + lg];
      #pragma unroll
      for(int r=0;r<4;r++){
        int kg = kbase + nt*16 + lg*4 + r;
        float sv = sa[nt][r]*sl2;
        float gv = qpl2 * kq[r];
        if(diag && kg > q){ sv = -__builtin_inff(); gv = -__builtin_inff(); }
        p1v[nt][r] = sv; p2v[nt][r] = gv;
      }
    }

    // ---- dual online softmax: in-lane 16-value reduce + 2 shuffles ----
    float mx = -__builtin_inff(), gx = -__builtin_inff();
    #pragma unroll
    for(int nt=0;nt<4;nt++){
      float a = fmaxf(fmaxf(p1v[nt][0],p1v[nt][1]), fmaxf(p1v[nt][2],p1v[nt][3]));
      float g = fmaxf(fmaxf(p2v[nt][0],p2v[nt][1]), fmaxf(p2v[nt][2],p2v[nt][3]));
      mx = fmaxf(mx, a); gx = fmaxf(gx, g);
    }
    mx = fmaxf(mx, __shfl_xor(mx,16)); mx = fmaxf(mx, __shfl_xor(mx,32));
    gx = fmaxf(gx, __shfl_xor(gx,16)); gx = fmaxf(gx, __shfl_xor(gx,32));
    float mn1 = fmaxf(m1, mx), mn2 = fmaxf(m2, gx);
    u64 grow = __ballot((mn1 > m1) | (mn2 > m2));
    if(grow){   // exact skip: rescale only when some row max grew
      float c1 = exp2f(m1 - mn1), c2 = exp2f(m2 - mn2);
      l1 *= c1; l2 *= c2; m1 = mn1; m2 = mn2;
      #pragma unroll
      for(int dt=0;dt<8;dt++){ a1[dt] *= c1; a2[dt] *= c2; }
    }
    float rs1 = 0.f, rs2 = 0.f;
    #pragma unroll
    for(int nt=0;nt<4;nt++){
      u16 e1b[4], e2b[4];
      #pragma unroll
      for(int r=0;r<4;r++){
        float e1 = exp2f(p1v[nt][r] - m1); rs1 += e1; e1b[r] = f2bf(e1);
        float e2 = exp2f(p2v[nt][r] - m2); rs2 += e2; e2b[r] = f2bf(e2);
      }
      u64 pk1 = (u64)e1b[0] | ((u64)e1b[1]<<16) | ((u64)e1b[2]<<32) | ((u64)e1b[3]<<48);
      u64 pk2 = (u64)e2b[0] | ((u64)e2b[1]<<16) | ((u64)e2b[2]<<32) | ((u64)e2b[3]<<48);
      int off = li*128 + ((nt*32 + lg*8) ^ ((li&7)<<4));
      *(u64*)((char*)Ps[w]  + off) = pk1;
      *(u64*)((char*)P2s[w] + off) = pk2;
    }
    rs1 += __shfl_xor(rs1,16); rs1 += __shfl_xor(rs1,32);
    rs2 += __shfl_xor(rs2,16); rs2 += __shfl_xor(rs2,32);
    l1 += rs1; l2 += rs2;

    // ---- O^T += V^T · P^T (both tables share the V fragment reads) ----
    #pragma unroll
    for(int kc=0;kc<2;kc++){
      int colb0 = kc*64 + lg*16;
      int poff = li*128 + (colb0 ^ ((li&7)<<4));
      bf16x8 pf1 = *(const bf16x8*)((const char*)Ps[w]  + poff);
      bf16x8 pf2 = *(const bf16x8*)((const char*)P2s[w] + poff);
      __builtin_amdgcn_s_setprio(1);
      #pragma unroll
      for(int dt=0;dt<8;dt++){
        int vrow = dt*16 + li;
        bf16x8 vf = *(const bf16x8*)((const char*)Vs[cur] + vrow*128 + (colb0 ^ ((vrow&7)<<4)));
        a1[dt] = mfma16(vf, pf1, a1[dt]);
        a2[dt] = mfma16(vf, pf2, a2[dt]);
      }
      __builtin_amdgcn_s_setprio(0);
    }
    __syncthreads();   // drains next-tile gload_lds (vmcnt) + publishes buffers
    cur ^= 1;
  }

  float rl1 = 1.0f/l1, rl2 = 1.0f/l2;
  float sh = hs[h];
  u16* obase = outp + (size_t)(b*TT + q)*CC + h*DD;
  #pragma unroll
  for(int dt=0;dt<8;dt++){
    u16 ob[4];
    #pragma unroll
    for(int r=0;r<4;r++){
      float o1 = a1[dt][r]*rl1;
      float o2 = a2[dt][r]*rl2;
      ob[r] = f2bf(o1 + sh*(o2-o1));
    }
    u64 pk = (u64)ob[0] | ((u64)ob[1]<<16) | ((u64)ob[2]<<32) | ((u64)ob[3]<<48);
    *(u64*)(obase + dt*16 + lg*4) = pk;
  }
}

extern "C" void kernel_launch(void* const* d_in, const int* in_sizes, int n_in,
                              void* d_out, int out_size, void* d_ws, size_t ws_size,
                              hipStream_t stream){
  (void)in_sizes; (void)n_in; (void)out_size; (void)ws_size;
  const float* x   = (const float*)d_in[0];
  const float* Wq  = (const float*)d_in[1];
  const float* Wk  = (const float*)d_in[2];
  const float* Wv  = (const float*)d_in[3];
  const float* Wo  = (const float*)d_in[4];
  const float* lng = (const float*)d_in[5];
  const float* lnb = (const float*)d_in[6];
  const float* hsc = (const float*)d_in[7];
  const float* hdr = (const float*)d_in[8];

  char* ws = (char*)d_ws;
  const size_t SZ = (size_t)8192*1024*2;       // 16 MiB per bf16 activation buffer
  u16* xn   = (u16*)ws;                        // reused as attn_out after QKV gemms
  u16* wbf  = (u16*)(ws + SZ);                 // 8 MiB: Wq|Wk|Wv|Wo bf16
  u16* Qb   = (u16*)(ws + SZ + 8388608);
  u16* Kb   = (u16*)(ws + 2*SZ + 8388608);
  u16* VT   = (u16*)(ws + 3*SZ + 8388608);     // (B,H,D,T)
  float* cosT = (float*)(ws + 4*SZ + 8388608);
  float* sinT = cosT + 131072;
  float* qp   = sinT + 131072;
  float* kp   = qp + 65536;

  ln_k<<<8192,256,0,stream>>>(x, lng, lnb, xn);
  wconv_k<<<4096,256,0,stream>>>(Wq,Wk,Wv,Wo,wbf);
  rope_tab_k<<<512,256,0,stream>>>(cosT,sinT);
  gemm_k<0><<<dim3(64,8),256,0,stream>>>(xn, wbf,          Qb, nullptr, nullptr);
  gemm_k<0><<<dim3(64,8),256,0,stream>>>(xn, wbf+1048576,  Kb, nullptr, nullptr);
  gemm_k<1><<<dim3(64,8),256,0,stream>>>(xn, wbf+2097152,  VT, nullptr, nullptr);
  rope_apply_k<<<8192,256,0,stream>>>(Qb,Kb,cosT,sinT);
  qpkp_k<<<256,256,0,stream>>>(Qb,Kb,hdr,qp,kp);
  attn_k<<<dim3(32,32),256,0,stream>>>(Qb,Kb,VT,qp,kp,hsc,xn);
  gemm_k<2><<<dim3(64,8),256,0,stream>>>(xn, wbf+3145728, nullptr, (float*)d_out, x);
}

// Round 3
// 312.038 us; speedup vs baseline: 1.7132x; 1.5106x over previous
//
#include <hip/hip_runtime.h>
#include <hip/hip_bf16.h>
#include <stdint.h>

#define BB 4
#define TT 2048
#define CC 1024
#define HH 8
#define DD 128

typedef unsigned short u16;
typedef unsigned int u32;
typedef unsigned long long u64;
typedef __attribute__((ext_vector_type(4))) float f32x4;
typedef __attribute__((ext_vector_type(16))) float f32x16;
typedef __attribute__((ext_vector_type(8))) __bf16 bf16x8;

__device__ __forceinline__ float bf2f(u16 u){ u32 x=((u32)u)<<16; float f; __builtin_memcpy(&f,&x,4); return f; }
__device__ __forceinline__ u16 f2bf(float f){ u32 x; __builtin_memcpy(&x,&f,4); x += 0x7fffu + ((x>>16)&1u); return (u16)(x>>16); }

__device__ __forceinline__ void gload16(const void* g, void* l){
  __builtin_amdgcn_global_load_lds((const __attribute__((address_space(1))) u32*)g,
                                   (__attribute__((address_space(3))) u32*)l, 16, 0, 0);
}
__device__ __forceinline__ f32x4 mfma16(bf16x8 a, bf16x8 b, f32x4 c){
  return __builtin_amdgcn_mfma_f32_16x16x32_bf16(a,b,c,0,0,0);
}
__device__ __forceinline__ f32x16 mfma32(bf16x8 a, bf16x8 b, f32x16 c){
  return __builtin_amdgcn_mfma_f32_32x32x16_bf16(a,b,c,0,0,0);
}
__device__ __forceinline__ u32 cvtpk(float lo, float hi){
  u32 r; asm("v_cvt_pk_bf16_f32 %0, %1, %2" : "=v"(r) : "v"(lo), "v"(hi)); return r;
}
__device__ __forceinline__ void pl32swap(u32& d, u32& s){
  asm volatile("v_permlane32_swap_b32 %0, %1" : "+v"(d), "+v"(s));
}
union FRAG { u32 u[4]; bf16x8 v; };

// ---------------- LayerNorm: f32 x -> bf16 xn ----------------
__global__ void ln_k(const float* __restrict__ x, const float* __restrict__ g,
                     const float* __restrict__ bta, u16* __restrict__ xn){
  int row = blockIdx.x, tid = threadIdx.x;
  const float4 v = ((const float4*)(x + (size_t)row*CC))[tid];
  float s = v.x+v.y+v.z+v.w;
  float ss = v.x*v.x+v.y*v.y+v.z*v.z+v.w*v.w;
  #pragma unroll
  for(int m=1;m<64;m<<=1){ s += __shfl_xor(s,m); ss += __shfl_xor(ss,m); }
  __shared__ float red[8];
  if((tid&63)==0){ red[tid>>6]=s; red[4+(tid>>6)]=ss; }
  __syncthreads();
  float ts = red[0]+red[1]+red[2]+red[3];
  float tss = red[4]+red[5]+red[6]+red[7];
  float mu = ts*(1.0f/CC);
  float rs = rsqrtf(tss*(1.0f/CC) - mu*mu + 1e-5f);
  int c0 = tid*4;
  ushort4 o;
  o.x = f2bf((v.x-mu)*rs*g[c0+0]+bta[c0+0]);
  o.y = f2bf((v.y-mu)*rs*g[c0+1]+bta[c0+1]);
  o.z = f2bf((v.z-mu)*rs*g[c0+2]+bta[c0+2]);
  o.w = f2bf((v.w-mu)*rs*g[c0+3]+bta[c0+3]);
  ((ushort4*)(xn + (size_t)row*CC))[tid] = o;
}

// ---------------- weights f32 -> bf16 ----------------
__global__ void wconv_k(const float* __restrict__ wq, const float* __restrict__ wk,
                        const float* __restrict__ wv, const float* __restrict__ wo,
                        u16* __restrict__ out){
  int i = blockIdx.x*256 + threadIdx.x;
  int sel = i>>18;
  const float* src = sel==0?wq: sel==1?wk: sel==2?wv:wo;
  float4 v = ((const float4*)src)[i & 262143];
  ushort4 o; o.x=f2bf(v.x); o.y=f2bf(v.y); o.z=f2bf(v.z); o.w=f2bf(v.w);
  ((ushort4*)out)[i] = o;
}

// ---------------- RoPE tables ----------------
__global__ void rope_tab_k(float* __restrict__ cosT, float* __restrict__ sinT){
  int i = blockIdx.x*256 + threadIdx.x;
  int t = i>>6, j = i&63;
  float inv = powf(10000.0f, -(float)(2*j)*(1.0f/128.0f));
  float a = (float)t * inv;
  cosT[i] = cosf(a);
  sinT[i] = sinf(a);
}

// ---------------- RoPE apply ----------------
__global__ void rope_apply_k(u16* __restrict__ Qb, u16* __restrict__ Kb,
                             const float* __restrict__ cosT, const float* __restrict__ sinT){
  int bt = blockIdx.x, tid = threadIdx.x;
  int t = bt & (TT-1);
  #pragma unroll
  for(int pp=0; pp<2; pp++){
    int p = tid*2+pp;
    int h = p>>6, d = p&63;
    size_t i1 = (size_t)bt*CC + h*DD + d;
    float c = cosT[t*64+d], s = sinT[t*64+d];
    float q1 = bf2f(Qb[i1]), q2 = bf2f(Qb[i1+64]);
    Qb[i1]    = f2bf(q1*c - q2*s);
    Qb[i1+64] = f2bf(q2*c + q1*s);
    float k1 = bf2f(Kb[i1]), k2 = bf2f(Kb[i1+64]);
    Kb[i1]    = f2bf(k1*c - k2*s);
    Kb[i1+64] = f2bf(k2*c + k1*s);
  }
}

// ---------------- qp/kp ----------------
__global__ void qpkp_k(const u16* __restrict__ Qb, const u16* __restrict__ Kb,
                       const float* __restrict__ dirs, float* __restrict__ qp, float* __restrict__ kp){
  int idx = blockIdx.x*256 + threadIdx.x;
  int b = idx>>14, rem = idx & 16383;
  int h = rem>>11, t = rem & 2047;
  size_t base = ((size_t)(b*TT + t))*CC + h*DD;
  float d0 = dirs[h*3], d1 = dirs[h*3+1], d2 = dirs[h*3+2];
  qp[idx] = bf2f(Qb[base])*d0 + bf2f(Qb[base+1])*d1 + bf2f(Qb[base+2])*d2;
  kp[idx] = bf2f(Kb[base])*d0 + bf2f(Kb[base+1])*d1 + bf2f(Kb[base+2])*d2;
}

// ---------------- GEMM ----------------
template<int MODE>
__global__ __launch_bounds__(256) void gemm_k(const u16* __restrict__ A, const u16* __restrict__ W,
                                              u16* __restrict__ outb, float* __restrict__ outf,
                                              const float* __restrict__ resid){
  __shared__ __align__(16) u16 As[128*64];
  __shared__ __align__(16) u16 Bs[128*64];
  const int K = CC;
  int m0 = blockIdx.x*128, n0 = blockIdx.y*128;
  int tid = threadIdx.x, w = tid>>6, l = tid&63;
  int li = l&15, lg = l>>4;
  int wm = w>>1, wn = w&1;
  f32x4 acc[4][4] = {};
  for(int k0=0; k0<K; k0+=64){
    #pragma unroll
    for(int i=0;i<4;i++){
      int L = (w*4+i)*1024 + l*16;
      int row = L>>7;
      int colb = (L&127) ^ ((row&7)<<4);
      gload16(A + ((size_t)(m0+row)*K + k0 + (colb>>1)), (char*)As + (w*4+i)*1024);
      gload16(W + ((size_t)(n0+row)*K + k0 + (colb>>1)), (char*)Bs + (w*4+i)*1024);
    }
    __syncthreads();
    #pragma unroll
    for(int kc=0;kc<2;kc++){
      bf16x8 af[4], bfr[4];
      #pragma unroll
      for(int mi=0;mi<4;mi++){
        int row = wm*64 + mi*16 + li;
        int colb = (kc*64 + lg*16) ^ ((row&7)<<4);
        af[mi] = *(const bf16x8*)((const char*)As + row*128 + colb);
      }
      #pragma unroll
      for(int ni=0;ni<4;ni++){
        int row = wn*64 + ni*16 + li;
        int colb = (kc*64 + lg*16) ^ ((row&7)<<4);
        bfr[ni] = *(const bf16x8*)((const char*)Bs + row*128 + colb);
      }
      #pragma unroll
      for(int mi=0;mi<4;mi++){
        #pragma unroll
        for(int ni=0;ni<4;ni++)
          acc[mi][ni] = mfma16(af[mi], bfr[ni], acc[mi][ni]);
      }
    }
    __syncthreads();
  }
  #pragma unroll
  for(int mi=0;mi<4;mi++){
    #pragma unroll
    for(int ni=0;ni<4;ni++){
      #pragma unroll
      for(int r=0;r<4;r++){
        int row = m0 + wm*64 + mi*16 + lg*4 + r;
        int col = n0 + wn*64 + ni*16 + li;
        float v = acc[mi][ni][r];
        if(MODE==0){
          outb[(size_t)row*CC + col] = f2bf(v);
        } else if(MODE==1){
          int hh = col>>7, dd = col&127, bb = row>>11, t = row&2047;
          outb[(((size_t)bb*HH+hh)*DD+dd)*TT + t] = f2bf(v);
        } else {
          size_t o = (size_t)row*CC + col;
          outf[o] = v + resid[o];
        }
      }
    }
  }
}

// ---------------- fused dual flash attention: mfma32, 32q/wave, register-P ----------------
// 8 waves/block; waves 0-3 -> strip p, waves 4-7 -> strip 15-p (uniform work pairing).
// K tile: Ks[64 rows][128 d] (256B rows); V^T tile: Vs[128 d][64 k] (128B rows); XOR swizzle ((row&7)<<4).
__global__ __launch_bounds__(512,2) void attn_k(const u16* __restrict__ Q, const u16* __restrict__ Kb,
                                                const u16* __restrict__ VT, const float* __restrict__ qp,
                                                const float* __restrict__ kp, const float* __restrict__ hs,
                                                u16* __restrict__ outp){
  __shared__ __align__(16) u16 Ks[2][64*128];
  __shared__ __align__(16) u16 Vs[2][128*64];
  int bid = blockIdx.x;
  int xcd = bid&7, slot = bid>>3;
  int bh = xcd*4 + (slot&3);      // all blocks of a bh group land on one XCD (L2 locality)
  int pair = slot>>2;             // 0..7
  int b = bh>>3, h = bh&7;
  int tid = threadIdx.x, w = tid>>6, l = tid&63;
  int l5 = l>>5, q31 = l&31;
  int strip = (w<4)? pair : (15-pair);
  int q0 = strip*128 + (w&3)*32;
  int q  = q0 + q31;
  int NT = 2*(16-pair);           // k-tiles needed by strip B (superset)

  // Q fragment: B-operand, outer q, d-slice l5*8 per 16-d block
  bf16x8 qf[8];
  {
    const u16* qbase = Q + ((size_t)(b*TT + q)*CC + h*DD);
    #pragma unroll
    for(int db=0;db<8;db++) qf[db] = *(const bf16x8*)(qbase + db*16 + l5*8);
  }
  const float L2E = 1.442695040888963f;
  const float sl2 = 0.08838834764831845f * L2E;
  // qp fragment (geo): slots {qh,qh,ql} on l5==0 lanes
  bf16x8 qpf;
  {
    float qs = qp[(size_t)bh*TT + q] * L2E;
    u16 qh = f2bf(qs); float qhf = bf2f(qh);
    u16 ql = f2bf(qs - qhf);
    FRAG fq; fq.u[0] = l5? 0u : ((u32)qh | ((u32)qh<<16));
    fq.u[1] = l5? 0u : (u32)ql; fq.u[2]=0; fq.u[3]=0;
    qpf = fq.v;
  }

  float m1=-__builtin_inff(), l1=0.f, m2=-__builtin_inff(), l2=0.f;
  f32x16 a1[4] = {}, a2[4] = {};
  const f32x16 zf = {};

  auto stage = [&](int kt, int buf){
    int kbase = kt*64;
    #pragma unroll
    for(int i=0;i<4;i++){
      int c = w*4+i;
      int L = c*1024 + l*16;
      if(c < 16){   // K tile: 16KB
        int row = L>>8;
        int colb = (L&255) ^ ((row&7)<<4);
        gload16(Kb + ((size_t)(b*TT + kbase + row)*CC + h*DD + (colb>>1)), (char*)Ks[buf] + c*1024);
      } else {      // V^T tile: 16KB
        int LV = L - 16384;
        int row = LV>>7;
        int colb = (LV&127) ^ ((row&7)<<4);
        gload16(VT + (((size_t)bh*DD + row)*TT + kbase + (colb>>1)), (char*)Vs[buf] + (c-16)*1024);
      }
    }
  };

  stage(0,0);
  __syncthreads();
  int cur = 0;

  for(int kt=0; kt<NT; ++kt){
    if(kt+1 < NT) stage(kt+1, cur^1);
    int kbase = kt*64;
    if(kbase <= q0+31){          // wave-uniform activity test
      #pragma unroll
      for(int t=0;t<2;t++){
        int ksub = kbase + t*32;
        if(ksub > q0+31) break;  // wave-uniform
        // ---- S^T = K·Q^T (32x32), two independent mfma chains ----
        f32x16 s0 = zf, s1a = zf;
        {
          int row = t*32 + q31;
          int swz = (row&7)<<4;
          const char* kbp = (const char*)Ks[cur] + row*256;
          __builtin_amdgcn_s_setprio(1);
          #pragma unroll
          for(int db=0;db<8;db+=2){
            bf16x8 kf0 = *(const bf16x8*)(kbp + ((db*32 + l5*16) ^ swz));
            bf16x8 kf1 = *(const bf16x8*)(kbp + (((db+1)*32 + l5*16) ^ swz));
            s0  = mfma32(kf0, qf[db],   s0);
            s1a = mfma32(kf1, qf[db+1], s1a);
          }
          __builtin_amdgcn_s_setprio(0);
        }
        // ---- geo scores via rank-1 mfma (hi/lo split, log2 domain) ----
        f32x16 gg;
        {
          float kpv = kp[(size_t)bh*TT + ksub + q31];
          u16 kh = f2bf(kpv); float khf = bf2f(kh);
          u16 kl = f2bf(kpv - khf);
          FRAG fk; fk.u[0] = l5? 0u : ((u32)kh | ((u32)kl<<16));
          fk.u[1] = l5? 0u : (u32)kh; fk.u[2]=0; fk.u[3]=0;
          gg = mfma32(fk.v, qpf, zf);
        }
        // ---- mask + scale ----
        bool needmask = (ksub + 31) > q0;
        float sv[16], gv[16];
        #pragma unroll
        for(int r=0;r<16;r++){
          int kg = ksub + (r&3) + 8*(r>>2) + 4*l5;
          float s = (s0[r] + s1a[r]) * sl2;
          float g = gg[r];
          if(needmask && kg > q){ s = -__builtin_inff(); g = -__builtin_inff(); }
          sv[r]=s; gv[r]=g;
        }
        // ---- dual online softmax (lane-local q) ----
        float mx=-__builtin_inff(), gx=-__builtin_inff();
        #pragma unroll
        for(int r=0;r<16;r++){ mx = fmaxf(mx, sv[r]); gx = fmaxf(gx, gv[r]); }
        mx = fmaxf(mx, __shfl_xor(mx,32));
        gx = fmaxf(gx, __shfl_xor(gx,32));
        float mn1 = fmaxf(m1, mx), mn2 = fmaxf(m2, gx);
        if(__ballot((mn1 > m1) | (mn2 > m2))){
          float c1 = exp2f(m1-mn1), c2 = exp2f(m2-mn2);
          l1 *= c1; l2 *= c2; m1 = mn1; m2 = mn2;
          #pragma unroll
          for(int dt=0;dt<4;dt++){ a1[dt] *= c1; a2[dt] *= c2; }
        }
        float rs1=0.f, rs2=0.f;
        float e1[16], e2[16];
        #pragma unroll
        for(int r=0;r<16;r++){
          e1[r] = exp2f(sv[r] - m1); rs1 += e1[r];
          e2[r] = exp2f(gv[r] - m2); rs2 += e2[r];
        }
        rs1 += __shfl_xor(rs1,32); rs2 += __shfl_xor(rs2,32);
        l1 += rs1; l2 += rs2;
        // ---- P -> bf16 B-fragments in-register (cvt_pk + permlane32_swap) ----
        u32 P1[8], P2[8];
        #pragma unroll
        for(int m=0;m<8;m++){ P1[m] = cvtpk(e1[2*m], e1[2*m+1]); P2[m] = cvtpk(e2[2*m], e2[2*m+1]); }
        pl32swap(P1[0],P1[2]); pl32swap(P1[1],P1[3]); pl32swap(P1[4],P1[6]); pl32swap(P1[5],P1[7]);
        pl32swap(P2[0],P2[2]); pl32swap(P2[1],P2[3]); pl32swap(P2[4],P2[6]); pl32swap(P2[5],P2[7]);
        // ---- O^T += V^T · P^T ----
        #pragma unroll
        for(int kb=0;kb<2;kb++){
          FRAG f1, f2;
          #pragma unroll
          for(int j=0;j<4;j++){ f1.u[j] = P1[kb*4+j]; f2.u[j] = P2[kb*4+j]; }
          bf16x8 pb1 = f1.v, pb2 = f2.v;
          __builtin_amdgcn_s_setprio(1);
          #pragma unroll
          for(int dt=0;dt<4;dt++){
            int row = dt*32 + q31;
            int colb = (t*64 + kb*32 + l5*16) ^ ((row&7)<<4);
            bf16x8 vf = *(const bf16x8*)((const char*)Vs[cur] + row*128 + colb);
            a1[dt] = mfma32(vf, pb1, a1[dt]);
            a2[dt] = mfma32(vf, pb2, a2[dt]);
          }
          __builtin_amdgcn_s_setprio(0);
        }
      }
    }
    __syncthreads();
    cur ^= 1;
  }

  float rl1 = 1.0f/l1, rl2 = 1.0f/l2;
  float sh = hs[h];
  u16* obase = outp + (size_t)(b*TT + q)*CC + h*DD;
  #pragma unroll
  for(int dt=0;dt<4;dt++){
    #pragma unroll
    for(int m=0;m<8;m++){
      float oa1 = a1[dt][2*m]*rl1,   oa2 = a2[dt][2*m]*rl2;
      float ob1 = a1[dt][2*m+1]*rl1, ob2 = a2[dt][2*m+1]*rl2;
      float oa = oa1 + sh*(oa2-oa1);
      float ob = ob1 + sh*(ob2-ob1);
      int d = dt*32 + (2*m&3) + 8*(m>>1) + 4*l5;
      *(u32*)(obase + d) = cvtpk(oa, ob);
    }
  }
}

extern "C" void kernel_launch(void* const* d_in, const int* in_sizes, int n_in,
                              void* d_out, int out_size, void* d_ws, size_t ws_size,
                              hipStream_t stream){
  (void)in_sizes; (void)n_in; (void)out_size; (void)ws_size;
  const float* x   = (const float*)d_in[0];
  const float* Wq  = (const float*)d_in[1];
  const float* Wk  = (const float*)d_in[2];
  const float* Wv  = (const float*)d_in[3];
  const float* Wo  = (const float*)d_in[4];
  const float* lng = (const float*)d_in[5];
  const float* lnb = (const float*)d_in[6];
  const float* hsc = (const float*)d_in[7];
  const float* hdr = (const float*)d_in[8];

  char* ws = (char*)d_ws;
  const size_t SZ = (size_t)8192*1024*2;
  u16* xn   = (u16*)ws;
  u16* wbf  = (u16*)(ws + SZ);
  u16* Qb   = (u16*)(ws + SZ + 8388608);
  u16* Kb   = (u16*)(ws + 2*SZ + 8388608);
  u16* VT   = (u16*)(ws + 3*SZ + 8388608);
  float* cosT = (float*)(ws + 4*SZ + 8388608);
  float* sinT = cosT + 131072;
  float* qp   = sinT + 131072;
  float* kp   = qp + 65536;

  ln_k<<<8192,256,0,stream>>>(x, lng, lnb, xn);
  wconv_k<<<4096,256,0,stream>>>(Wq,Wk,Wv,Wo,wbf);
  rope_tab_k<<<512,256,0,stream>>>(cosT,sinT);
  gemm_k<0><<<dim3(64,8),256,0,stream>>>(xn, wbf,          Qb, nullptr, nullptr);
  gemm_k<0><<<dim3(64,8),256,0,stream>>>(xn, wbf+1048576,  Kb, nullptr, nullptr);
  gemm_k<1><<<dim3(64,8),256,0,stream>>>(xn, wbf+2097152,  VT, nullptr, nullptr);
  rope_apply_k<<<8192,256,0,stream>>>(Qb,Kb,cosT,sinT);
  qpkp_k<<<256,256,0,stream>>>(Qb,Kb,hdr,qp,kp);
  attn_k<<<256,512,0,stream>>>(Qb,Kb,VT,qp,kp,hsc,xn);
  gemm_k<2><<<dim3(64,8),256,0,stream>>>(xn, wbf+3145728, nullptr, (float*)d_out, x);
}

// Round 4
// 311.216 us; speedup vs baseline: 1.7177x; 1.0026x over previous
//
#include <hip/hip_runtime.h>
#include <hip/hip_bf16.h>
#include <stdint.h>

#define BB 4
#define TT 2048
#define CC 1024
#define HH 8
#define DD 128

typedef unsigned short u16;
typedef unsigned int u32;
typedef unsigned long long u64;
typedef __attribute__((ext_vector_type(4))) float f32x4;
typedef __attribute__((ext_vector_type(16))) float f32x16;
typedef __attribute__((ext_vector_type(8))) __bf16 bf16x8;

__device__ __forceinline__ float bf2f(u16 u){ u32 x=((u32)u)<<16; float f; __builtin_memcpy(&f,&x,4); return f; }
__device__ __forceinline__ u16 f2bf(float f){ u32 x; __builtin_memcpy(&x,&f,4); x += 0x7fffu + ((x>>16)&1u); return (u16)(x>>16); }

__device__ __forceinline__ void gload16(const void* g, void* l){
  __builtin_amdgcn_global_load_lds((const __attribute__((address_space(1))) u32*)g,
                                   (__attribute__((address_space(3))) u32*)l, 16, 0, 0);
}
__device__ __forceinline__ f32x4 mfma16(bf16x8 a, bf16x8 b, f32x4 c){
  return __builtin_amdgcn_mfma_f32_16x16x32_bf16(a,b,c,0,0,0);
}
__device__ __forceinline__ f32x16 mfma32(bf16x8 a, bf16x8 b, f32x16 c){
  return __builtin_amdgcn_mfma_f32_32x32x16_bf16(a,b,c,0,0,0);
}
__device__ __forceinline__ u32 cvtpk(float lo, float hi){
  u32 r; asm("v_cvt_pk_bf16_f32 %0, %1, %2" : "=v"(r) : "v"(lo), "v"(hi)); return r;
}
__device__ __forceinline__ void pl32swap(u32& d, u32& s){
  asm volatile("v_permlane32_swap_b32 %0, %1" : "+v"(d), "+v"(s));
}
union FRAG { u32 u[4]; bf16x8 v; };

// ---------------- LayerNorm: f32 x -> bf16 xn ----------------
__global__ void ln_k(const float* __restrict__ x, const float* __restrict__ g,
                     const float* __restrict__ bta, u16* __restrict__ xn){
  int row = blockIdx.x, tid = threadIdx.x;
  const float4 v = ((const float4*)(x + (size_t)row*CC))[tid];
  float s = v.x+v.y+v.z+v.w;
  float ss = v.x*v.x+v.y*v.y+v.z*v.z+v.w*v.w;
  #pragma unroll
  for(int m=1;m<64;m<<=1){ s += __shfl_xor(s,m); ss += __shfl_xor(ss,m); }
  __shared__ float red[8];
  if((tid&63)==0){ red[tid>>6]=s; red[4+(tid>>6)]=ss; }
  __syncthreads();
  float ts = red[0]+red[1]+red[2]+red[3];
  float tss = red[4]+red[5]+red[6]+red[7];
  float mu = ts*(1.0f/CC);
  float rs = rsqrtf(tss*(1.0f/CC) - mu*mu + 1e-5f);
  int c0 = tid*4;
  ushort4 o;
  o.x = f2bf((v.x-mu)*rs*g[c0+0]+bta[c0+0]);
  o.y = f2bf((v.y-mu)*rs*g[c0+1]+bta[c0+1]);
  o.z = f2bf((v.z-mu)*rs*g[c0+2]+bta[c0+2]);
  o.w = f2bf((v.w-mu)*rs*g[c0+3]+bta[c0+3]);
  ((ushort4*)(xn + (size_t)row*CC))[tid] = o;
}

// ---------------- weights f32 -> bf16 ----------------
__global__ void wconv_k(const float* __restrict__ wq, const float* __restrict__ wk,
                        const float* __restrict__ wv, const float* __restrict__ wo,
                        u16* __restrict__ out){
  int i = blockIdx.x*256 + threadIdx.x;
  int sel = i>>18;
  const float* src = sel==0?wq: sel==1?wk: sel==2?wv:wo;
  float4 v = ((const float4*)src)[i & 262143];
  ushort4 o; o.x=f2bf(v.x); o.y=f2bf(v.y); o.z=f2bf(v.z); o.w=f2bf(v.w);
  ((ushort4*)out)[i] = o;
}

// ---------------- RoPE tables ----------------
__global__ void rope_tab_k(float* __restrict__ cosT, float* __restrict__ sinT){
  int i = blockIdx.x*256 + threadIdx.x;
  int t = i>>6, j = i&63;
  float inv = powf(10000.0f, -(float)(2*j)*(1.0f/128.0f));
  float a = (float)t * inv;
  cosT[i] = cosf(a);
  sinT[i] = sinf(a);
}

// ---------------- RoPE apply ----------------
__global__ void rope_apply_k(u16* __restrict__ Qb, u16* __restrict__ Kb,
                             const float* __restrict__ cosT, const float* __restrict__ sinT){
  int bt = blockIdx.x, tid = threadIdx.x;
  int t = bt & (TT-1);
  #pragma unroll
  for(int pp=0; pp<2; pp++){
    int p = tid*2+pp;
    int h = p>>6, d = p&63;
    size_t i1 = (size_t)bt*CC + h*DD + d;
    float c = cosT[t*64+d], s = sinT[t*64+d];
    float q1 = bf2f(Qb[i1]), q2 = bf2f(Qb[i1+64]);
    Qb[i1]    = f2bf(q1*c - q2*s);
    Qb[i1+64] = f2bf(q2*c + q1*s);
    float k1 = bf2f(Kb[i1]), k2 = bf2f(Kb[i1+64]);
    Kb[i1]    = f2bf(k1*c - k2*s);
    Kb[i1+64] = f2bf(k2*c + k1*s);
  }
}

// ---------------- qp/kp ----------------
__global__ void qpkp_k(const u16* __restrict__ Qb, const u16* __restrict__ Kb,
                       const float* __restrict__ dirs, float* __restrict__ qp, float* __restrict__ kp){
  int idx = blockIdx.x*256 + threadIdx.x;
  int b = idx>>14, rem = idx & 16383;
  int h = rem>>11, t = rem & 2047;
  size_t base = ((size_t)(b*TT + t))*CC + h*DD;
  float d0 = dirs[h*3], d1 = dirs[h*3+1], d2 = dirs[h*3+2];
  qp[idx] = bf2f(Qb[base])*d0 + bf2f(Qb[base+1])*d1 + bf2f(Qb[base+2])*d2;
  kp[idx] = bf2f(Kb[base])*d0 + bf2f(Kb[base+1])*d1 + bf2f(Kb[base+2])*d2;
}

// ---------------- GEMM ----------------
template<int MODE>
__global__ __launch_bounds__(256) void gemm_k(const u16* __restrict__ A, const u16* __restrict__ W,
                                              u16* __restrict__ outb, float* __restrict__ outf,
                                              const float* __restrict__ resid){
  __shared__ __align__(16) u16 As[128*64];
  __shared__ __align__(16) u16 Bs[128*64];
  const int K = CC;
  int m0 = blockIdx.x*128, n0 = blockIdx.y*128;
  int tid = threadIdx.x, w = tid>>6, l = tid&63;
  int li = l&15, lg = l>>4;
  int wm = w>>1, wn = w&1;
  f32x4 acc[4][4] = {};
  for(int k0=0; k0<K; k0+=64){
    #pragma unroll
    for(int i=0;i<4;i++){
      int L = (w*4+i)*1024 + l*16;
      int row = L>>7;
      int colb = (L&127) ^ ((row&7)<<4);
      gload16(A + ((size_t)(m0+row)*K + k0 + (colb>>1)), (char*)As + (w*4+i)*1024);
      gload16(W + ((size_t)(n0+row)*K + k0 + (colb>>1)), (char*)Bs + (w*4+i)*1024);
    }
    __syncthreads();
    #pragma unroll
    for(int kc=0;kc<2;kc++){
      bf16x8 af[4], bfr[4];
      #pragma unroll
      for(int mi=0;mi<4;mi++){
        int row = wm*64 + mi*16 + li;
        int colb = (kc*64 + lg*16) ^ ((row&7)<<4);
        af[mi] = *(const bf16x8*)((const char*)As + row*128 + colb);
      }
      #pragma unroll
      for(int ni=0;ni<4;ni++){
        int row = wn*64 + ni*16 + li;
        int colb = (kc*64 + lg*16) ^ ((row&7)<<4);
        bfr[ni] = *(const bf16x8*)((const char*)Bs + row*128 + colb);
      }
      #pragma unroll
      for(int mi=0;mi<4;mi++){
        #pragma unroll
        for(int ni=0;ni<4;ni++)
          acc[mi][ni] = mfma16(af[mi], bfr[ni], acc[mi][ni]);
      }
    }
    __syncthreads();
  }
  #pragma unroll
  for(int mi=0;mi<4;mi++){
    #pragma unroll
    for(int ni=0;ni<4;ni++){
      #pragma unroll
      for(int r=0;r<4;r++){
        int row = m0 + wm*64 + mi*16 + lg*4 + r;
        int col = n0 + wn*64 + ni*16 + li;
        float v = acc[mi][ni][r];
        if(MODE==0){
          outb[(size_t)row*CC + col] = f2bf(v);
        } else if(MODE==1){
          int hh = col>>7, dd = col&127, bb = row>>11, t = row&2047;
          outb[(((size_t)bb*HH+hh)*DD+dd)*TT + t] = f2bf(v);
        } else {
          size_t o = (size_t)row*CC + col;
          outf[o] = v + resid[o];
        }
      }
    }
  }
}

// ---------------- fused dual flash attention: barrier-free, direct-L2 fragments ----------------
// 1024 blocks x 128 thr (2 waves). Block -> (bh, strip of 64 q); wave w owns 32 q.
// No LDS, no __syncthreads: each wave streams K/V fragments straight from L2.
__global__ __launch_bounds__(128,2) void attn_k(const u16* __restrict__ Q, const u16* __restrict__ Kb,
                                                const u16* __restrict__ VT, const float* __restrict__ qp,
                                                const float* __restrict__ kp, const float* __restrict__ hs,
                                                u16* __restrict__ outp){
  int bid = blockIdx.x;
  int xcd = bid&7, r = bid>>3;          // r: 0..127
  int bh = xcd*4 + (r&3);               // 4 bh groups per XCD (K/V L2-resident)
  int strip = 31 - (r>>2);              // 31..0: longest strips dispatch first
  int b = bh>>3, h = bh&7;
  int tid = threadIdx.x, w = tid>>6, l = tid&63;
  int l5 = l>>5, q31 = l&31;
  int q0 = strip*64 + w*32;
  int q  = q0 + q31;
  int NT = strip+1;                     // 64-k tiles

  // Q fragment (B-operand): outer q, contraction d
  bf16x8 qf[8];
  {
    const u16* qbase = Q + ((size_t)(b*TT + q)*CC + h*DD);
    #pragma unroll
    for(int db=0;db<8;db++) qf[db] = *(const bf16x8*)(qbase + db*16 + l5*8);
  }
  const float L2E = 1.442695040888963f;
  const float sl2 = 0.08838834764831845f * L2E;
  bf16x8 qpf;
  {
    float qs = qp[(size_t)bh*TT + q] * L2E;
    u16 qh = f2bf(qs); float qhf = bf2f(qh);
    u16 ql = f2bf(qs - qhf);
    FRAG fq; fq.u[0] = l5? 0u : ((u32)qh | ((u32)qh<<16));
    fq.u[1] = l5? 0u : (u32)ql; fq.u[2]=0; fq.u[3]=0;
    qpf = fq.v;
  }

  // streaming base pointers (advance once per 64-k round)
  const u16* kb0 = Kb + ((size_t)b*TT + q31)*CC + h*DD + l5*8;        // k-rows q31+kbase
  const u16* kb1 = kb0 + (size_t)32*CC;                                // +32 k-rows
  const u16* vt0 = VT + ((size_t)bh*DD +  0 + q31)*TT + l5*8;
  const u16* vt1 = VT + ((size_t)bh*DD + 32 + q31)*TT + l5*8;
  const u16* vt2 = VT + ((size_t)bh*DD + 64 + q31)*TT + l5*8;
  const u16* vt3 = VT + ((size_t)bh*DD + 96 + q31)*TT + l5*8;
  const float* kpp = kp + (size_t)bh*TT + q31;

  float m1=-__builtin_inff(), l1=0.f, m2=-__builtin_inff(), l2=0.f;
  f32x16 a1[4] = {}, a2[4] = {};
  const f32x16 zf = {};

  for(int kt=0; kt<NT; ++kt){
    int kbase = kt*64;
    #pragma unroll
    for(int t=0;t<2;t++){
      int ksub = kbase + t*32;
      if(t==1 && ksub > q0+31) continue;       // wave-uniform: only last tile of w=0 waves

      // ---- K fragments straight from global (L2) ----
      const u16* kb = t ? kb1 : kb0;
      bf16x8 kf0 = *(const bf16x8*)(kb +   0);
      bf16x8 kf1 = *(const bf16x8*)(kb +  16);
      bf16x8 kf2 = *(const bf16x8*)(kb +  32);
      bf16x8 kf3 = *(const bf16x8*)(kb +  48);
      bf16x8 kf4 = *(const bf16x8*)(kb +  64);
      bf16x8 kf5 = *(const bf16x8*)(kb +  80);
      bf16x8 kf6 = *(const bf16x8*)(kb +  96);
      bf16x8 kf7 = *(const bf16x8*)(kb + 112);

      // ---- S^T = K·Q^T (two independent chains) ----
      f32x16 s0 = zf, s1a = zf;
      __builtin_amdgcn_s_setprio(1);
      s0  = mfma32(kf0, qf[0], s0);  s1a = mfma32(kf1, qf[1], s1a);
      s0  = mfma32(kf2, qf[2], s0);  s1a = mfma32(kf3, qf[3], s1a);
      s0  = mfma32(kf4, qf[4], s0);  s1a = mfma32(kf5, qf[5], s1a);
      s0  = mfma32(kf6, qf[6], s0);  s1a = mfma32(kf7, qf[7], s1a);
      __builtin_amdgcn_s_setprio(0);

      // ---- geo scores via rank-1 mfma (hi/lo split, log2 domain) ----
      f32x16 gg;
      {
        float kpv = kpp[t*32];
        u16 kh = f2bf(kpv); float khf = bf2f(kh);
        u16 kl = f2bf(kpv - khf);
        FRAG fk; fk.u[0] = l5? 0u : ((u32)kh | ((u32)kl<<16));
        fk.u[1] = l5? 0u : (u32)kh; fk.u[2]=0; fk.u[3]=0;
        gg = mfma32(fk.v, qpf, zf);
      }

      // ---- scale (+ causal mask only on diagonal subtiles) ----
      float sv[16], gv[16];
      #pragma unroll
      for(int rr=0;rr<16;rr++){ sv[rr] = (s0[rr]+s1a[rr])*sl2; gv[rr] = gg[rr]; }
      if(ksub + 31 > q0){                       // wave-uniform diagonal test
        #pragma unroll
        for(int rr=0;rr<16;rr++){
          int kg = ksub + (rr&3) + 8*(rr>>2) + 4*l5;
          if(kg > q){ sv[rr] = -__builtin_inff(); gv[rr] = -__builtin_inff(); }
        }
      }

      // ---- dual online softmax, lane-local q, defer-max (THR=8 in log2) ----
      float mx=-__builtin_inff(), gx=-__builtin_inff();
      #pragma unroll
      for(int rr=0;rr<16;rr++){ mx = fmaxf(mx, sv[rr]); gx = fmaxf(gx, gv[rr]); }
      mx = fmaxf(mx, __shfl_xor(mx,32));
      gx = fmaxf(gx, __shfl_xor(gx,32));
      if(__ballot((mx > m1+8.f) | (gx > m2+8.f))){
        float mn1 = fmaxf(m1,mx), mn2 = fmaxf(m2,gx);
        float c1 = exp2f(m1-mn1), c2 = exp2f(m2-mn2);
        l1 *= c1; l2 *= c2; m1 = mn1; m2 = mn2;
        #pragma unroll
        for(int dt=0;dt<4;dt++){ a1[dt] *= c1; a2[dt] *= c2; }
      }
      float rs1=0.f, rs2=0.f;
      float e1[16], e2[16];
      #pragma unroll
      for(int rr=0;rr<16;rr++){
        e1[rr] = exp2f(sv[rr] - m1); rs1 += e1[rr];
        e2[rr] = exp2f(gv[rr] - m2); rs2 += e2[rr];
      }
      rs1 += __shfl_xor(rs1,32); rs2 += __shfl_xor(rs2,32);
      l1 += rs1; l2 += rs2;

      // ---- P -> bf16 B-fragments in-register ----
      u32 P1[8], P2[8];
      #pragma unroll
      for(int m=0;m<8;m++){ P1[m] = cvtpk(e1[2*m], e1[2*m+1]); P2[m] = cvtpk(e2[2*m], e2[2*m+1]); }
      pl32swap(P1[0],P1[2]); pl32swap(P1[1],P1[3]); pl32swap(P1[4],P1[6]); pl32swap(P1[5],P1[7]);
      pl32swap(P2[0],P2[2]); pl32swap(P2[1],P2[3]); pl32swap(P2[4],P2[6]); pl32swap(P2[5],P2[7]);

      // ---- O^T += V^T · P^T (V fragments straight from global) ----
      #pragma unroll
      for(int kb2=0;kb2<2;kb2++){
        FRAG f1, f2;
        #pragma unroll
        for(int j=0;j<4;j++){ f1.u[j] = P1[kb2*4+j]; f2.u[j] = P2[kb2*4+j]; }
        bf16x8 pb1 = f1.v, pb2 = f2.v;
        int ko = t*32 + kb2*16;                  // elem offset in k
        bf16x8 vf0 = *(const bf16x8*)(vt0 + ko);
        bf16x8 vf1 = *(const bf16x8*)(vt1 + ko);
        bf16x8 vf2 = *(const bf16x8*)(vt2 + ko);
        bf16x8 vf3 = *(const bf16x8*)(vt3 + ko);
        __builtin_amdgcn_s_setprio(1);
        a1[0] = mfma32(vf0, pb1, a1[0]);  a2[0] = mfma32(vf0, pb2, a2[0]);
        a1[1] = mfma32(vf1, pb1, a1[1]);  a2[1] = mfma32(vf1, pb2, a2[1]);
        a1[2] = mfma32(vf2, pb1, a1[2]);  a2[2] = mfma32(vf2, pb2, a2[2]);
        a1[3] = mfma32(vf3, pb1, a1[3]);  a2[3] = mfma32(vf3, pb2, a2[3]);
        __builtin_amdgcn_s_setprio(0);
      }
    }
    kb0 += (size_t)64*CC; kb1 += (size_t)64*CC;
    vt0 += 64; vt1 += 64; vt2 += 64; vt3 += 64;
    kpp += 64;
  }

  float rl1 = 1.0f/l1, rl2 = 1.0f/l2;
  float sh = hs[h];
  u16* obase = outp + (size_t)(b*TT + q)*CC + h*DD;
  #pragma unroll
  for(int dt=0;dt<4;dt++){
    #pragma unroll
    for(int m=0;m<8;m++){
      float oa1 = a1[dt][2*m]*rl1,   oa2 = a2[dt][2*m]*rl2;
      float ob1 = a1[dt][2*m+1]*rl1, ob2 = a2[dt][2*m+1]*rl2;
      float oa = oa1 + sh*(oa2-oa1);
      float ob = ob1 + sh*(ob2-ob1);
      int d = dt*32 + (2*m&3) + 8*(m>>1) + 4*l5;
      *(u32*)(obase + d) = cvtpk(oa, ob);
    }
  }
}

extern "C" void kernel_launch(void* const* d_in, const int* in_sizes, int n_in,
                              void* d_out, int out_size, void* d_ws, size_t ws_size,
                              hipStream_t stream){
  (void)in_sizes; (void)n_in; (void)out_size; (void)ws_size;
  const float* x   = (const float*)d_in[0];
  const float* Wq  = (const float*)d_in[1];
  const float* Wk  = (const float*)d_in[2];
  const float* Wv  = (const float*)d_in[3];
  const float* Wo  = (const float*)d_in[4];
  const float* lng = (const float*)d_in[5];
  const float* lnb = (const float*)d_in[6];
  const float* hsc = (const float*)d_in[7];
  const float* hdr = (const float*)d_in[8];

  char* ws = (char*)d_ws;
  const size_t SZ = (size_t)8192*1024*2;
  u16* xn   = (u16*)ws;
  u16* wbf  = (u16*)(ws + SZ);
  u16* Qb   = (u16*)(ws + SZ + 8388608);
  u16* Kb   = (u16*)(ws + 2*SZ + 8388608);
  u16* VT   = (u16*)(ws + 3*SZ + 8388608);
  float* cosT = (float*)(ws + 4*SZ + 8388608);
  float* sinT = cosT + 131072;
  float* qp   = sinT + 131072;
  float* kp   = qp + 65536;

  ln_k<<<8192,256,0,stream>>>(x, lng, lnb, xn);
  wconv_k<<<4096,256,0,stream>>>(Wq,Wk,Wv,Wo,wbf);
  rope_tab_k<<<512,256,0,stream>>>(cosT,sinT);
  gemm_k<0><<<dim3(64,8),256,0,stream>>>(xn, wbf,          Qb, nullptr, nullptr);
  gemm_k<0><<<dim3(64,8),256,0,stream>>>(xn, wbf+1048576,  Kb, nullptr, nullptr);
  gemm_k<1><<<dim3(64,8),256,0,stream>>>(xn, wbf+2097152,  VT, nullptr, nullptr);
  rope_apply_k<<<8192,256,0,stream>>>(Qb,Kb,cosT,sinT);
  qpkp_k<<<256,256,0,stream>>>(Qb,Kb,hdr,qp,kp);
  attn_k<<<1024,128,0,stream>>>(Qb,Kb,VT,qp,kp,hsc,xn);
  gemm_k<2><<<dim3(64,8),256,0,stream>>>(xn, wbf+3145728, nullptr, (float*)d_out, x);
}